// Round 21
// baseline (377.706 us; speedup 1.0000x reference)
//
#include <hip/hip_runtime.h>
#include <math.h>

#define CCH 48
#define NST 16
#define VOX (64*64*64)
#define LOG2E 1.44269504088896340736f

typedef __attribute__((ext_vector_type(8))) short bf16x8_t;
typedef __attribute__((ext_vector_type(4))) float f32x4_t;
typedef unsigned short ushort_t;

__device__ __forceinline__ float softplus_f(float s) {
    return fmaxf(s, 0.f) + log1pf(__expf(-fabsf(s)));
}

__device__ __forceinline__ ushort_t f2bf(float f) {
    unsigned u = __float_as_uint(f);
    unsigned r = (u + 0x7FFF + ((u >> 16) & 1)) >> 16;
    return (ushort_t)r;
}

// r15-proven dpp_add form. LEDGER: the "fusable" variant (old=src,
// bound_ctrl=false) was tested in isolation in r20 and REGRESSED 119.5->131us
// -- do not re-try. This form (old=0, bound_ctrl=true) is load-bearing.
template<int CTRL>
__device__ __forceinline__ float dpp_add(float x) {
    int v = __builtin_amdgcn_update_dpp(0, __float_as_int(x), CTRL, 0xF, 0xF, true);
    return x + __int_as_float(v);
}

__global__ __launch_bounds__(256) void k_transpose_in(const float* __restrict__ x,
                                                      float* __restrict__ xt) {
    __shared__ float tile[CCH * 65];
    int v0 = blockIdx.x * 64;
    int t = threadIdx.x;
#pragma unroll
    for (int i = 0; i < 12; ++i) {
        int idx = t + i * 256;
        int c = idx >> 6, v = idx & 63;
        tile[c * 65 + v] = x[c * VOX + v0 + v];
    }
    __syncthreads();
#pragma unroll
    for (int i = 0; i < 12; ++i) {
        int idx = t + i * 256;
        int v = idx / CCH, c = idx - v * CCH;
        xt[(v0 + v) * CCH + c] = tile[c * 65 + v];
    }
}

__global__ __launch_bounds__(256) void k_transpose_out(const float* __restrict__ yws,
                                                       float* __restrict__ out) {
    __shared__ float tile[CCH * 65];
    int v0 = blockIdx.x * 64;
    int t = threadIdx.x;
#pragma unroll
    for (int i = 0; i < 12; ++i) {
        int idx = t + i * 256;
        int v = idx / CCH, c = idx - v * CCH;
        tile[c * 65 + v] = yws[(v0 + v) * CCH + c];
    }
    __syncthreads();
#pragma unroll
    for (int i = 0; i < 12; ++i) {
        int idx = t + i * 256;
        int c = idx >> 6, v = idx & 63;
        out[c * VOX + v0 + v] = tile[c * 65 + v];
    }
}

// LDS layout (float offsets):
#define OFF_XS    0        // 3072  xs fp32 [l][48]
#define OFF_XB    3072     // 2304  xs bf16 [l][72] (u16; k 48..63 zero pad)
#define OFF_WB16  5376     // 2880  W bf16 [80][72] (rows 0..47 dt^T, 48..63 B^T, 64..79 C^T)
#define OFF_DTS   8256     // 3264  dtsT[c*68+l]
#define OFF_UX    11520    // 3264  uxT[c*68+l]
#define OFF_BC    14784    // 1088  BcsT[n*68+l]
#define OFF_CC    15872    // 1088  CcsT[n*68+l]
#define OFF_YS    3072     // 3072  ys[l*48+c] (aliases XB+WB16 after MFMA phase)
#define SMEM_FLOATS 16960  // 67,840 B -> 2 blocks/CU

// Ledger (empirical, this kernel):
//  launch_bounds: arg2=6 -> RA cap 40 VGPR. arg2=4/2 -> 64 VGPR -> crosses
//    m69 waves/CU halving -> 1 block/CU, 1.9x latency (r8/r9). KEEP (768,6).
//  r19 baseline: 119.5us/scan, total 347us. VALUBusy 79%, MfmaUtil 0.9%.
//  exp: __builtin_amdgcn_exp2f = bare v_exp_f32 (r19, -5.5us). libm exp2f =
//    REGRESSION (r18, +38us: precise-path fixup). __expf = mul+exp (ok).
//  dpp_add: old=0/bound_ctrl=1 form is load-bearing; "fusable" old=src form
//    REGRESSED +11.5us (r20 isolated). ror{1,2,4} 8-lane WRONG (r10);
//    xor-involutions (0xB1/0x4E/0x141 and quad_perm pairs) verified (r12).
//  THIS round: scan 2-state/8-lane -> 4-state/4-lane quad (dpp 9->6 instrs,
//    p-combine amortized over 4 states; float2 loads to fit 40-VGPR cap).
//  MFMA D-layout: col=lane&15, row=(lane>>4)*4+reg (m89-verified).
__global__ __launch_bounds__(768, 6) void k_scan(
    const float* __restrict__ xt, float* __restrict__ yws,
    const float* __restrict__ A_log, const float* __restrict__ W_dt,
    const float* __restrict__ b_dt, const float* __restrict__ W_B,
    const float* __restrict__ W_C, const float* __restrict__ D_skip,
    int dir, int stride_v, int accumulate)
{
    __shared__ __align__(16) float smem[SMEM_FLOATS];
    float* xs   = smem + OFF_XS;
    float* dtsT = smem + OFF_DTS;
    float* uxT  = smem + OFF_UX;
    float* BcsT = smem + OFF_BC;
    float* CcsT = smem + OFF_CC;
    float* ys   = smem + OFF_YS;
    ushort_t* xb = (ushort_t*)(smem + OFF_XB);
    ushort_t* wb = (ushort_t*)(smem + OFF_WB16);

    int t = threadIdx.x;
    int lid = blockIdx.x;
    int a = lid >> 6, b = lid & 63;
    int vbase;
    if (dir == 0) vbase = lid;                 // step stride 4096 (along D)
    else if (dir == 1) vbase = a * 4096 + b;   // step stride 64   (along H)
    else vbase = a * 4096 + b * 64;            // step stride 1    (along W)

    const float* wdt_g = W_dt + dir * CCH * CCH;
    const float* wB_g  = W_B + dir * CCH * NST;
    const float* wC_g  = W_C + dir * CCH * NST;

    // ---- stage line of x: fp32 + bf16 copies ----
    {
        int q = t % 12, l = t / 12;
        float4 v = *(const float4*)&xt[(vbase + l * stride_v) * CCH + 4 * q];
        *(float4*)&xs[l * CCH + 4 * q] = v;
        unsigned p0 = (unsigned)f2bf(v.x) | ((unsigned)f2bf(v.y) << 16);
        unsigned p1 = (unsigned)f2bf(v.z) | ((unsigned)f2bf(v.w) << 16);
        unsigned* d = (unsigned*)&xb[l * 72 + 4 * q];
        d[0] = p0; d[1] = p1;
    }
    // ---- stage weights bf16, transposed: wb[row][k], row = output index ----
    for (int idx = t; idx < 3840; idx += 768) {
        float v; int row, k;
        if (idx < 2304)      { k = idx / 48;       row = idx % 48;        v = wdt_g[idx]; }
        else if (idx < 3072) { int j = idx - 2304; k = j >> 4; row = 48 + (j & 15); v = wB_g[j]; }
        else                 { int j = idx - 3072; k = j >> 4; row = 64 + (j & 15); v = wC_g[j]; }
        wb[row * 72 + k] = f2bf(v);
    }
    // ---- zero K-pads (k = 48..63) ----
    for (int i = t; i < 80 * 16; i += 768) wb[(i >> 4) * 72 + 48 + (i & 15)] = 0;
    for (int i = t; i < 64 * 16; i += 768) xb[(i >> 4) * 72 + 48 + (i & 15)] = 0;
    __syncthreads();

    // ---- MFMA projections: O[80][64] = W(80x48) * x^T(48x64), bf16 in fp32 out.
    {
        int w = t >> 6, lane = t & 63;
        if (w < 10) {
            int r16 = lane & 15, g = lane >> 4;
#pragma unroll
            for (int tt = 0; tt < 2; ++tt) {
                int tile = w * 2 + tt;
                int tm = tile >> 2, tn = tile & 3;
                const ushort_t* ap = &wb[(tm * 16 + r16) * 72 + g * 8];
                const ushort_t* bp = &xb[(tn * 16 + r16) * 72 + g * 8];
                bf16x8_t A0 = *(const bf16x8_t*)ap;
                bf16x8_t A1 = *(const bf16x8_t*)(ap + 32);
                bf16x8_t B0 = *(const bf16x8_t*)bp;
                bf16x8_t B1 = *(const bf16x8_t*)(bp + 32);
                f32x4_t acc = {0.f, 0.f, 0.f, 0.f};
                acc = __builtin_amdgcn_mfma_f32_16x16x32_bf16(A0, B0, acc, 0, 0, 0);
                acc = __builtin_amdgcn_mfma_f32_16x16x32_bf16(A1, B1, acc, 0, 0, 0);
                int col = tn * 16 + r16;
                float* outp;
                if (tm < 3)       outp = &dtsT[(tm * 16 + g * 4) * 68 + col];
                else if (tm == 3) outp = &BcsT[(g * 4) * 68 + col];
                else              outp = &CcsT[(g * 4) * 68 + col];
                outp[0 * 68] = acc[0];
                outp[1 * 68] = acc[1];
                outp[2 * 68] = acc[2];
                outp[3 * 68] = acc[3];
            }
        }
    }
    __syncthreads();

    // ---- pointwise: bias + softplus on dt; ux = dt * x ----
    {
        int c = t % CCH, l0 = t / CCH;   // l0 0..15, owns l = 4*l0..4*l0+3
        float bias = b_dt[dir * CCH + c];
        float4 dv = *(const float4*)&dtsT[c * 68 + 4 * l0];
        float4 dtv, uxv;
        dtv.x = softplus_f(dv.x + bias); uxv.x = dtv.x * xs[(4 * l0 + 0) * CCH + c];
        dtv.y = softplus_f(dv.y + bias); uxv.y = dtv.y * xs[(4 * l0 + 1) * CCH + c];
        dtv.z = softplus_f(dv.z + bias); uxv.z = dtv.z * xs[(4 * l0 + 2) * CCH + c];
        dtv.w = softplus_f(dv.w + bias); uxv.w = dtv.w * xs[(4 * l0 + 3) * CCH + c];
        *(float4*)&dtsT[c * 68 + 4 * l0] = dtv;
        *(float4*)&uxT[c * 68 + 4 * l0]  = uxv;
    }
    __syncthreads();

    // ---- sequential scan: 192 threads, FOUR states (c, nh+4j) j=0..3 ----
    // Quad lanes nh=0..3 hold n = {nh, nh+4, nh+8, nh+12} -> the 4-lane quad
    // covers all 16 n exactly once. Reduce = 2 quad_perm xor-involutions
    // (0xB1 = xor1, 0x4E = xor2), both r12-verified direction-free.
    // dt/ux rows shared by all 4 states; float2 loads keep live set < 40 VGPR.
    if (t < 192) {
        int cc = t >> 2, nh = t & 3;
        const float* alog = A_log + dir * CCH * NST + cc * NST + nh;
        float a0 = -expf(alog[0])  * LOG2E;
        float a1 = -expf(alog[4])  * LOG2E;
        float a2 = -expf(alog[8])  * LOG2E;
        float a3 = -expf(alog[12]) * LOG2E;
        const float2* dt2 = (const float2*)&dtsT[cc * 68];
        const float2* ux2 = (const float2*)&uxT[cc * 68];
        const float2* Br0 = (const float2*)&BcsT[(nh +  0) * 68];
        const float2* Br1 = (const float2*)&BcsT[(nh +  4) * 68];
        const float2* Br2 = (const float2*)&BcsT[(nh +  8) * 68];
        const float2* Br3 = (const float2*)&BcsT[(nh + 12) * 68];
        const float2* Cr0 = (const float2*)&CcsT[(nh +  0) * 68];
        const float2* Cr1 = (const float2*)&CcsT[(nh +  4) * 68];
        const float2* Cr2 = (const float2*)&CcsT[(nh +  8) * 68];
        const float2* Cr3 = (const float2*)&CcsT[(nh + 12) * 68];
        float h0 = 0.f, h1 = 0.f, h2 = 0.f, h3 = 0.f;

#define STEP(COMP, LIDX)                                                    \
        {                                                                   \
            h0 = fmaf(__builtin_amdgcn_exp2f(dtv.COMP * a0), h0,            \
                      uxv.COMP * b0v.COMP);                                 \
            h1 = fmaf(__builtin_amdgcn_exp2f(dtv.COMP * a1), h1,            \
                      uxv.COMP * b1v.COMP);                                 \
            h2 = fmaf(__builtin_amdgcn_exp2f(dtv.COMP * a2), h2,            \
                      uxv.COMP * b2v.COMP);                                 \
            h3 = fmaf(__builtin_amdgcn_exp2f(dtv.COMP * a3), h3,            \
                      uxv.COMP * b3v.COMP);                                 \
            float p = h0 * c0v.COMP;                                        \
            p = fmaf(h1, c1v.COMP, p);                                      \
            p = fmaf(h2, c2v.COMP, p);                                      \
            p = fmaf(h3, c3v.COMP, p);                                      \
            p = dpp_add<0xB1>(p);                                           \
            p = dpp_add<0x4E>(p);                                           \
            if (nh == 0) ys[(LIDX) * CCH + cc] = p;                         \
        }

#pragma unroll
        for (int l2 = 0; l2 < 32; ++l2) {
            float2 dtv = dt2[l2];
            float2 uxv = ux2[l2];
            float2 b0v = Br0[l2], b1v = Br1[l2], b2v = Br2[l2], b3v = Br3[l2];
            float2 c0v = Cr0[l2], c1v = Cr1[l2], c2v = Cr2[l2], c3v = Cr3[l2];
            STEP(x, 2 * l2 + 0)
            STEP(y, 2 * l2 + 1)
        }
#undef STEP
    }
    __syncthreads();

    // ---- add skip term and write/accumulate to yws ----
    {
        int q = t % 12, l = t / 12;
        float4 yv = *(const float4*)&ys[l * CCH + 4 * q];
        float4 xv = *(const float4*)&xs[l * CCH + 4 * q];
        float4 dv = *(const float4*)&D_skip[dir * CCH + 4 * q];
        yv.x = fmaf(dv.x, xv.x, yv.x);
        yv.y = fmaf(dv.y, xv.y, yv.y);
        yv.z = fmaf(dv.z, xv.z, yv.z);
        yv.w = fmaf(dv.w, xv.w, yv.w);
        float* gp = &yws[(vbase + l * stride_v) * CCH + 4 * q];
        if (accumulate) {
            float4 old = *(const float4*)gp;
            yv.x += old.x; yv.y += old.y; yv.z += old.z; yv.w += old.w;
        }
        *(float4*)gp = yv;
    }
}

extern "C" void kernel_launch(void* const* d_in, const int* in_sizes, int n_in,
                              void* d_out, int out_size, void* d_ws, size_t ws_size,
                              hipStream_t stream) {
    const float* x      = (const float*)d_in[0];
    const float* A_log  = (const float*)d_in[1];
    const float* W_dt   = (const float*)d_in[2];
    const float* b_dt   = (const float*)d_in[3];
    const float* W_B    = (const float*)d_in[4];
    const float* W_C    = (const float*)d_in[5];
    const float* D_skip = (const float*)d_in[6];
    float* out = (float*)d_out;

    float* xt  = (float*)d_ws;
    float* yws = xt + (size_t)VOX * CCH;

    k_transpose_in<<<VOX / 64, 256, 0, stream>>>(x, xt);
    k_scan<<<4096, 768, 0, stream>>>(xt, yws, A_log, W_dt, b_dt, W_B, W_C, D_skip, 0, 4096, 0);
    k_scan<<<4096, 768, 0, stream>>>(xt, yws, A_log, W_dt, b_dt, W_B, W_C, D_skip, 1, 64, 1);
    k_scan<<<4096, 768, 0, stream>>>(xt, yws, A_log, W_dt, b_dt, W_B, W_C, D_skip, 2, 1, 1);
    k_transpose_out<<<VOX / 64, 256, 0, stream>>>(yws, out);
}

// Round 22
// 338.836 us; speedup vs baseline: 1.1147x; 1.1147x over previous
//
#include <hip/hip_runtime.h>
#include <math.h>

#define CCH 48
#define NST 16
#define VOX (64*64*64)
#define LOG2E 1.44269504088896340736f

typedef __attribute__((ext_vector_type(8))) short bf16x8_t;
typedef __attribute__((ext_vector_type(4))) float f32x4_t;
typedef unsigned short ushort_t;

__device__ __forceinline__ float softplus_f(float s) {
    return fmaxf(s, 0.f) + log1pf(__expf(-fabsf(s)));
}

__device__ __forceinline__ ushort_t f2bf(float f) {
    unsigned u = __float_as_uint(f);
    unsigned r = (u + 0x7FFF + ((u >> 16) & 1)) >> 16;
    return (ushort_t)r;
}

// r15-proven dpp_add form. LEDGER: "fusable" variant (old=src,bound_ctrl=0)
// REGRESSED +11.5us (r20, isolated). This form is load-bearing.
template<int CTRL>
__device__ __forceinline__ float dpp_add(float x) {
    int v = __builtin_amdgcn_update_dpp(0, __float_as_int(x), CTRL, 0xF, 0xF, true);
    return x + __int_as_float(v);
}

__global__ __launch_bounds__(256) void k_transpose_in(const float* __restrict__ x,
                                                      float* __restrict__ xt) {
    __shared__ float tile[CCH * 65];
    int v0 = blockIdx.x * 64;
    int t = threadIdx.x;
#pragma unroll
    for (int i = 0; i < 12; ++i) {
        int idx = t + i * 256;
        int c = idx >> 6, v = idx & 63;
        tile[c * 65 + v] = x[c * VOX + v0 + v];
    }
    __syncthreads();
#pragma unroll
    for (int i = 0; i < 12; ++i) {
        int idx = t + i * 256;
        int v = idx / CCH, c = idx - v * CCH;
        xt[(v0 + v) * CCH + c] = tile[c * 65 + v];
    }
}

// LDS layout (float offsets):
#define OFF_XS    0        // 3072  xs fp32 [l][48]
#define OFF_XB    3072     // 2304  xs bf16 [l][72] (u16; k 48..63 zero pad)
#define OFF_WB16  5376     // 2880  W bf16 [80][72] (rows 0..47 dt^T, 48..63 B^T, 64..79 C^T)
#define OFF_DTS   8256     // 3264  dtsT[c*68+l]
#define OFF_UX    11520    // 3264  uxT[c*68+l]
#define OFF_BC    14784    // 1088  BcsT[n*68+l]
#define OFF_CC    15872    // 1088  CcsT[n*68+l]
#define OFF_YS    3072     // 3072  ys[l*48+c] (aliases XB+WB16 after MFMA phase)
#define OFF_YF    8256     // 3328  yf[l*52+c] (dir2 only; aliases dts/ux after scan)
#define SMEM_FLOATS 16960  // 67,840 B -> 2 blocks/CU

// Ledger (empirical, this kernel):
//  launch_bounds: arg2=6 -> RA cap 40 VGPR; arg2=4/2 -> 64 VGPR -> 1 block/CU
//    (m69 halving), 1.9x latency (r8/r9). KEEP (768,6), live-set <= ~32.
//  r19 baseline: 119.5us/scan, total 347us. VALUBusy 79%, MfmaUtil 0.9%.
//  exp: __builtin_amdgcn_exp2f = bare v_exp_f32 (r19, -5.5us). libm exp2f =
//    REGRESSION (r18 +38us). dpp_add old=0/bound_ctrl=1 load-bearing (r20).
//  scan structure: 2-state/384-thr/6-wave is a LOCAL OPTIMUM: 4-state/192-thr
//    REGRESSED +11us (r21: latency-bound at 3 waves); fusable dpp +11.5us
//    (r20); libm exp2 +38us (r18). Do not micro-opt scan further.
//  THIS round: drop k_transpose_out; dir2 epilogue writes final [C][DHW]
//    directly (2-pass: coalesced yws read -> yf stride-52 -> coalesced out).
//  Cross-lane: xor-involutions 0xB1/0x4E/0x141 verified (r12); ror 8-lane
//    subsets WRONG (r10). MFMA D: col=lane&15, row=(lane>>4)*4+reg (m89).
__global__ __launch_bounds__(768, 6) void k_scan(
    const float* __restrict__ xt, float* __restrict__ yws,
    const float* __restrict__ A_log, const float* __restrict__ W_dt,
    const float* __restrict__ b_dt, const float* __restrict__ W_B,
    const float* __restrict__ W_C, const float* __restrict__ D_skip,
    float* __restrict__ outf,
    int dir, int stride_v, int mode)   // mode: 0=write yws, 1=accum yws, 2=final->outf
{
    __shared__ __align__(16) float smem[SMEM_FLOATS];
    float* xs   = smem + OFF_XS;
    float* dtsT = smem + OFF_DTS;
    float* uxT  = smem + OFF_UX;
    float* BcsT = smem + OFF_BC;
    float* CcsT = smem + OFF_CC;
    float* ys   = smem + OFF_YS;
    float* yf   = smem + OFF_YF;
    ushort_t* xb = (ushort_t*)(smem + OFF_XB);
    ushort_t* wb = (ushort_t*)(smem + OFF_WB16);

    int t = threadIdx.x;
    int lid = blockIdx.x;
    int a = lid >> 6, b = lid & 63;
    int vbase;
    if (dir == 0) vbase = lid;                 // step stride 4096 (along D)
    else if (dir == 1) vbase = a * 4096 + b;   // step stride 64   (along H)
    else vbase = a * 4096 + b * 64;            // step stride 1    (along W)

    const float* wdt_g = W_dt + dir * CCH * CCH;
    const float* wB_g  = W_B + dir * CCH * NST;
    const float* wC_g  = W_C + dir * CCH * NST;

    // ---- stage line of x: fp32 + bf16 copies ----
    {
        int q = t % 12, l = t / 12;
        float4 v = *(const float4*)&xt[(vbase + l * stride_v) * CCH + 4 * q];
        *(float4*)&xs[l * CCH + 4 * q] = v;
        unsigned p0 = (unsigned)f2bf(v.x) | ((unsigned)f2bf(v.y) << 16);
        unsigned p1 = (unsigned)f2bf(v.z) | ((unsigned)f2bf(v.w) << 16);
        unsigned* d = (unsigned*)&xb[l * 72 + 4 * q];
        d[0] = p0; d[1] = p1;
    }
    // ---- stage weights bf16, transposed: wb[row][k], row = output index ----
    for (int idx = t; idx < 3840; idx += 768) {
        float v; int row, k;
        if (idx < 2304)      { k = idx / 48;       row = idx % 48;        v = wdt_g[idx]; }
        else if (idx < 3072) { int j = idx - 2304; k = j >> 4; row = 48 + (j & 15); v = wB_g[j]; }
        else                 { int j = idx - 3072; k = j >> 4; row = 64 + (j & 15); v = wC_g[j]; }
        wb[row * 72 + k] = f2bf(v);
    }
    // ---- zero K-pads (k = 48..63) ----
    for (int i = t; i < 80 * 16; i += 768) wb[(i >> 4) * 72 + 48 + (i & 15)] = 0;
    for (int i = t; i < 64 * 16; i += 768) xb[(i >> 4) * 72 + 48 + (i & 15)] = 0;
    __syncthreads();

    // ---- MFMA projections: O[80][64] = W(80x48) * x^T(48x64), bf16 in fp32 out.
    {
        int w = t >> 6, lane = t & 63;
        if (w < 10) {
            int r16 = lane & 15, g = lane >> 4;
#pragma unroll
            for (int tt = 0; tt < 2; ++tt) {
                int tile = w * 2 + tt;
                int tm = tile >> 2, tn = tile & 3;
                const ushort_t* ap = &wb[(tm * 16 + r16) * 72 + g * 8];
                const ushort_t* bp = &xb[(tn * 16 + r16) * 72 + g * 8];
                bf16x8_t A0 = *(const bf16x8_t*)ap;
                bf16x8_t A1 = *(const bf16x8_t*)(ap + 32);
                bf16x8_t B0 = *(const bf16x8_t*)bp;
                bf16x8_t B1 = *(const bf16x8_t*)(bp + 32);
                f32x4_t acc = {0.f, 0.f, 0.f, 0.f};
                acc = __builtin_amdgcn_mfma_f32_16x16x32_bf16(A0, B0, acc, 0, 0, 0);
                acc = __builtin_amdgcn_mfma_f32_16x16x32_bf16(A1, B1, acc, 0, 0, 0);
                int col = tn * 16 + r16;
                float* outp;
                if (tm < 3)       outp = &dtsT[(tm * 16 + g * 4) * 68 + col];
                else if (tm == 3) outp = &BcsT[(g * 4) * 68 + col];
                else              outp = &CcsT[(g * 4) * 68 + col];
                outp[0 * 68] = acc[0];
                outp[1 * 68] = acc[1];
                outp[2 * 68] = acc[2];
                outp[3 * 68] = acc[3];
            }
        }
    }
    __syncthreads();

    // ---- pointwise: bias + softplus on dt; ux = dt * x ----
    {
        int c = t % CCH, l0 = t / CCH;
        float bias = b_dt[dir * CCH + c];
        float4 dv = *(const float4*)&dtsT[c * 68 + 4 * l0];
        float4 dtv, uxv;
        dtv.x = softplus_f(dv.x + bias); uxv.x = dtv.x * xs[(4 * l0 + 0) * CCH + c];
        dtv.y = softplus_f(dv.y + bias); uxv.y = dtv.y * xs[(4 * l0 + 1) * CCH + c];
        dtv.z = softplus_f(dv.z + bias); uxv.z = dtv.z * xs[(4 * l0 + 2) * CCH + c];
        dtv.w = softplus_f(dv.w + bias); uxv.w = dtv.w * xs[(4 * l0 + 3) * CCH + c];
        *(float4*)&dtsT[c * 68 + 4 * l0] = dtv;
        *(float4*)&uxT[c * 68 + 4 * l0]  = uxv;
    }
    __syncthreads();

    // ---- sequential scan: 384 threads, TWO states (c,nh) and (c,nh+8) ----
    // (r19 verbatim -- 2-state/6-wave local optimum, see ledger)
    if (t < 384) {
        int cc = t >> 3, nh = t & 7;
        float a0 = -expf(A_log[dir * CCH * NST + cc * NST + nh]) * LOG2E;
        float a1 = -expf(A_log[dir * CCH * NST + cc * NST + nh + 8]) * LOG2E;
        const float4* dt4 = (const float4*)&dtsT[cc * 68];
        const float4* ux4 = (const float4*)&uxT[cc * 68];
        const float4* B4a = (const float4*)&BcsT[nh * 68];
        const float4* B4b = (const float4*)&BcsT[(nh + 8) * 68];
        const float4* C4a = (const float4*)&CcsT[nh * 68];
        const float4* C4b = (const float4*)&CcsT[(nh + 8) * 68];
        float h0 = 0.f, h1 = 0.f;

#define STEP(COMP, LIDX)                                                    \
        {                                                                   \
            float e0 = __builtin_amdgcn_exp2f(dtv.COMP * a0);               \
            float e1 = __builtin_amdgcn_exp2f(dtv.COMP * a1);               \
            h0 = fmaf(e0, h0, uxv.COMP * Bva.COMP);                         \
            h1 = fmaf(e1, h1, uxv.COMP * Bvb.COMP);                         \
            float p = fmaf(h1, Cvb.COMP, h0 * Cva.COMP);                    \
            p = dpp_add<0xB1>(p);                                           \
            p = dpp_add<0x4E>(p);                                           \
            p = dpp_add<0x141>(p);                                          \
            if (nh == 0) ys[(LIDX) * CCH + cc] = p;                         \
        }

#pragma unroll
        for (int l4 = 0; l4 < 16; ++l4) {
            float4 dtv = dt4[l4];
            float4 uxv = ux4[l4];
            float4 Bva = B4a[l4];
            float4 Bvb = B4b[l4];
            float4 Cva = C4a[l4];
            float4 Cvb = C4b[l4];
            STEP(x, l4 * 4 + 0)
            STEP(y, l4 * 4 + 1)
            STEP(z, l4 * 4 + 2)
            STEP(w, l4 * 4 + 3)
        }
#undef STEP
    }
    __syncthreads();

    // ---- epilogue ----
    if (mode != 2) {
        // dir0/dir1: add skip and write/accumulate yws (coalesced)
        int q = t % 12, l = t / 12;
        float4 yv = *(const float4*)&ys[l * CCH + 4 * q];
        float4 xv = *(const float4*)&xs[l * CCH + 4 * q];
        float4 dv = *(const float4*)&D_skip[dir * CCH + 4 * q];
        yv.x = fmaf(dv.x, xv.x, yv.x);
        yv.y = fmaf(dv.y, xv.y, yv.y);
        yv.z = fmaf(dv.z, xv.z, yv.z);
        yv.w = fmaf(dv.w, xv.w, yv.w);
        float* gp = &yws[(vbase + l * stride_v) * CCH + 4 * q];
        if (mode == 1) {
            float4 old = *(const float4*)gp;
            yv.x += old.x; yv.y += old.y; yv.z += old.z; yv.w += old.w;
        }
        *(float4*)gp = yv;
    } else {
        // dir2 FINAL: pass 1 -- (q,l) map: coalesced yws read + skip + ys,
        // store to yf (stride 52, float4-aligned, bank-spread).
        {
            int q = t % 12, l = t / 12;
            float4 yv = *(const float4*)&ys[l * CCH + 4 * q];
            float4 xv = *(const float4*)&xs[l * CCH + 4 * q];
            float4 dv = *(const float4*)&D_skip[dir * CCH + 4 * q];
            float4 ov = *(const float4*)&yws[(vbase + l * stride_v) * CCH + 4 * q];
            yv.x = fmaf(dv.x, xv.x, yv.x) + ov.x;
            yv.y = fmaf(dv.y, xv.y, yv.y) + ov.y;
            yv.z = fmaf(dv.z, xv.z, yv.z) + ov.z;
            yv.w = fmaf(dv.w, xv.w, yv.w) + ov.w;
            *(float4*)&yf[l * 52 + 4 * q] = yv;
        }
        __syncthreads();
        // pass 2 -- (c,l0) map: transpose in LDS, coalesced float4 out-write.
        // line is voxel-contiguous (dir2 stride 1): out[c*VOX + vbase + 4*l0].
        {
            int l0 = t & 15, c = t >> 4;
            float4 o;
            o.x = yf[(4 * l0 + 0) * 52 + c];
            o.y = yf[(4 * l0 + 1) * 52 + c];
            o.z = yf[(4 * l0 + 2) * 52 + c];
            o.w = yf[(4 * l0 + 3) * 52 + c];
            *(float4*)&outf[(size_t)c * VOX + vbase + 4 * l0] = o;
        }
    }
}

extern "C" void kernel_launch(void* const* d_in, const int* in_sizes, int n_in,
                              void* d_out, int out_size, void* d_ws, size_t ws_size,
                              hipStream_t stream) {
    const float* x      = (const float*)d_in[0];
    const float* A_log  = (const float*)d_in[1];
    const float* W_dt   = (const float*)d_in[2];
    const float* b_dt   = (const float*)d_in[3];
    const float* W_B    = (const float*)d_in[4];
    const float* W_C    = (const float*)d_in[5];
    const float* D_skip = (const float*)d_in[6];
    float* out = (float*)d_out;

    float* xt  = (float*)d_ws;
    float* yws = xt + (size_t)VOX * CCH;

    k_transpose_in<<<VOX / 64, 256, 0, stream>>>(x, xt);
    k_scan<<<4096, 768, 0, stream>>>(xt, yws, A_log, W_dt, b_dt, W_B, W_C, D_skip,
                                     out, 0, 4096, 0);
    k_scan<<<4096, 768, 0, stream>>>(xt, yws, A_log, W_dt, b_dt, W_B, W_C, D_skip,
                                     out, 1, 64, 1);
    k_scan<<<4096, 768, 0, stream>>>(xt, yws, A_log, W_dt, b_dt, W_B, W_C, D_skip,
                                     out, 2, 1, 2);
}

// Round 23
// 332.680 us; speedup vs baseline: 1.1353x; 1.0185x over previous
//
#include <hip/hip_runtime.h>
#include <math.h>

#define CCH 48
#define NST 16
#define VOX (64*64*64)
#define LOG2E 1.44269504088896340736f

typedef __attribute__((ext_vector_type(8))) short bf16x8_t;
typedef __attribute__((ext_vector_type(4))) float f32x4_t;
typedef unsigned short ushort_t;

__device__ __forceinline__ float softplus_f(float s) {
    return fmaxf(s, 0.f) + log1pf(__expf(-fabsf(s)));
}

__device__ __forceinline__ ushort_t f2bf(float f) {
    unsigned u = __float_as_uint(f);
    unsigned r = (u + 0x7FFF + ((u >> 16) & 1)) >> 16;
    return (ushort_t)r;
}

// r15-proven dpp_add form. LEDGER: "fusable" variant (old=src,bound_ctrl=0)
// REGRESSED +11.5us (r20, isolated). This form is load-bearing.
template<int CTRL>
__device__ __forceinline__ float dpp_add(float x) {
    int v = __builtin_amdgcn_update_dpp(0, __float_as_int(x), CTRL, 0xF, 0xF, true);
    return x + __int_as_float(v);
}

__global__ __launch_bounds__(256) void k_transpose_in(const float* __restrict__ x,
                                                      float* __restrict__ xt) {
    __shared__ float tile[CCH * 65];
    int v0 = blockIdx.x * 64;
    int t = threadIdx.x;
#pragma unroll
    for (int i = 0; i < 12; ++i) {
        int idx = t + i * 256;
        int c = idx >> 6, v = idx & 63;
        tile[c * 65 + v] = x[c * VOX + v0 + v];
    }
    __syncthreads();
#pragma unroll
    for (int i = 0; i < 12; ++i) {
        int idx = t + i * 256;
        int v = idx / CCH, c = idx - v * CCH;
        xt[(v0 + v) * CCH + c] = tile[c * 65 + v];
    }
}

// LDS layout (float offsets):
#define OFF_XS    0        // 3072  xs fp32 [l][48]
#define OFF_XB    3072     // 2304  xs bf16 [l][72] (u16; k 48..63 zero pad)
#define OFF_WB16  5376     // 2880  W bf16 [80][72] (rows 0..47 dt^T, 48..63 B^T, 64..79 C^T)
#define OFF_DTS   8256     // 3264  dtsT[c*68+l]
#define OFF_UX    11520    // 3264  uxT[c*68+l]
#define OFF_BC    14784    // 1088  BcsT[n*68+l]
#define OFF_CC    15872    // 1088  CcsT[n*68+l]
#define OFF_YS    3072     // 3072  ys[l*48+c] (aliases XB+WB16 after MFMA phase)
#define OFF_YF    8256     // 3328  yf[l*52+c] (MODE 2 only; aliases dts/ux after scan)
#define SMEM_FLOATS 16960  // 67,840 B -> 2 blocks/CU

// Ledger (empirical, this kernel):
//  launch_bounds: arg2=6 -> RA cap 40 VGPR; arg2=4/2 -> 64 VGPR -> 1 block/CU
//    (m69 halving), 1.9x latency (r8/r9). KEEP (768,6), live-set <= ~32.
//  r19: 119.5us/scan. r22 (fused out-write, runtime mode branch): transpose_out
//    eliminated (-8us total) BUT all scans +4.8us & conflicts 3.08e6->5.96e6 --
//    runtime-mode barrier-in-branch perturbed codegen for ALL modes.
//    THIS round: template<int MODE> so each mode gets clean codegen.
//  exp: __builtin_amdgcn_exp2f = bare v_exp_f32 (r19). libm exp2f REGRESSED
//    (r18 +38us). dpp_add old=0/bound_ctrl=1 load-bearing (r20).
//  scan structure: 2-state/384-thr/6-wave is a LOCAL OPTIMUM (r20/r21 both
//    regressed). Do not micro-opt scan further.
//  Cross-lane: xor-involutions 0xB1/0x4E/0x141 verified (r12); ror 8-lane
//    subsets WRONG (r10). MFMA D: col=lane&15, row=(lane>>4)*4+reg (m89).
template<int MODE>   // 0 = write yws, 1 = accumulate yws, 2 = final -> outf
__global__ __launch_bounds__(768, 6) void k_scan(
    const float* __restrict__ xt, float* __restrict__ yws,
    const float* __restrict__ A_log, const float* __restrict__ W_dt,
    const float* __restrict__ b_dt, const float* __restrict__ W_B,
    const float* __restrict__ W_C, const float* __restrict__ D_skip,
    float* __restrict__ outf,
    int dir, int stride_v)
{
    __shared__ __align__(16) float smem[SMEM_FLOATS];
    float* xs   = smem + OFF_XS;
    float* dtsT = smem + OFF_DTS;
    float* uxT  = smem + OFF_UX;
    float* BcsT = smem + OFF_BC;
    float* CcsT = smem + OFF_CC;
    float* ys   = smem + OFF_YS;
    float* yf   = smem + OFF_YF;
    ushort_t* xb = (ushort_t*)(smem + OFF_XB);
    ushort_t* wb = (ushort_t*)(smem + OFF_WB16);

    int t = threadIdx.x;
    int lid = blockIdx.x;
    int a = lid >> 6, b = lid & 63;
    int vbase;
    if (dir == 0) vbase = lid;                 // step stride 4096 (along D)
    else if (dir == 1) vbase = a * 4096 + b;   // step stride 64   (along H)
    else vbase = a * 4096 + b * 64;            // step stride 1    (along W)

    const float* wdt_g = W_dt + dir * CCH * CCH;
    const float* wB_g  = W_B + dir * CCH * NST;
    const float* wC_g  = W_C + dir * CCH * NST;

    // ---- stage line of x: fp32 + bf16 copies ----
    {
        int q = t % 12, l = t / 12;
        float4 v = *(const float4*)&xt[(vbase + l * stride_v) * CCH + 4 * q];
        *(float4*)&xs[l * CCH + 4 * q] = v;
        unsigned p0 = (unsigned)f2bf(v.x) | ((unsigned)f2bf(v.y) << 16);
        unsigned p1 = (unsigned)f2bf(v.z) | ((unsigned)f2bf(v.w) << 16);
        unsigned* d = (unsigned*)&xb[l * 72 + 4 * q];
        d[0] = p0; d[1] = p1;
    }
    // ---- stage weights bf16, transposed: wb[row][k], row = output index ----
    for (int idx = t; idx < 3840; idx += 768) {
        float v; int row, k;
        if (idx < 2304)      { k = idx / 48;       row = idx % 48;        v = wdt_g[idx]; }
        else if (idx < 3072) { int j = idx - 2304; k = j >> 4; row = 48 + (j & 15); v = wB_g[j]; }
        else                 { int j = idx - 3072; k = j >> 4; row = 64 + (j & 15); v = wC_g[j]; }
        wb[row * 72 + k] = f2bf(v);
    }
    // ---- zero K-pads (k = 48..63) ----
    for (int i = t; i < 80 * 16; i += 768) wb[(i >> 4) * 72 + 48 + (i & 15)] = 0;
    for (int i = t; i < 64 * 16; i += 768) xb[(i >> 4) * 72 + 48 + (i & 15)] = 0;
    __syncthreads();

    // ---- MFMA projections: O[80][64] = W(80x48) * x^T(48x64), bf16 in fp32 out.
    {
        int w = t >> 6, lane = t & 63;
        if (w < 10) {
            int r16 = lane & 15, g = lane >> 4;
#pragma unroll
            for (int tt = 0; tt < 2; ++tt) {
                int tile = w * 2 + tt;
                int tm = tile >> 2, tn = tile & 3;
                const ushort_t* ap = &wb[(tm * 16 + r16) * 72 + g * 8];
                const ushort_t* bp = &xb[(tn * 16 + r16) * 72 + g * 8];
                bf16x8_t A0 = *(const bf16x8_t*)ap;
                bf16x8_t A1 = *(const bf16x8_t*)(ap + 32);
                bf16x8_t B0 = *(const bf16x8_t*)bp;
                bf16x8_t B1 = *(const bf16x8_t*)(bp + 32);
                f32x4_t acc = {0.f, 0.f, 0.f, 0.f};
                acc = __builtin_amdgcn_mfma_f32_16x16x32_bf16(A0, B0, acc, 0, 0, 0);
                acc = __builtin_amdgcn_mfma_f32_16x16x32_bf16(A1, B1, acc, 0, 0, 0);
                int col = tn * 16 + r16;
                float* outp;
                if (tm < 3)       outp = &dtsT[(tm * 16 + g * 4) * 68 + col];
                else if (tm == 3) outp = &BcsT[(g * 4) * 68 + col];
                else              outp = &CcsT[(g * 4) * 68 + col];
                outp[0 * 68] = acc[0];
                outp[1 * 68] = acc[1];
                outp[2 * 68] = acc[2];
                outp[3 * 68] = acc[3];
            }
        }
    }
    __syncthreads();

    // ---- pointwise: bias + softplus on dt; ux = dt * x ----
    {
        int c = t % CCH, l0 = t / CCH;
        float bias = b_dt[dir * CCH + c];
        float4 dv = *(const float4*)&dtsT[c * 68 + 4 * l0];
        float4 dtv, uxv;
        dtv.x = softplus_f(dv.x + bias); uxv.x = dtv.x * xs[(4 * l0 + 0) * CCH + c];
        dtv.y = softplus_f(dv.y + bias); uxv.y = dtv.y * xs[(4 * l0 + 1) * CCH + c];
        dtv.z = softplus_f(dv.z + bias); uxv.z = dtv.z * xs[(4 * l0 + 2) * CCH + c];
        dtv.w = softplus_f(dv.w + bias); uxv.w = dtv.w * xs[(4 * l0 + 3) * CCH + c];
        *(float4*)&dtsT[c * 68 + 4 * l0] = dtv;
        *(float4*)&uxT[c * 68 + 4 * l0]  = uxv;
    }
    __syncthreads();

    // ---- sequential scan: 384 threads, TWO states (c,nh) and (c,nh+8) ----
    // (r19 verbatim -- 2-state/6-wave local optimum, see ledger)
    if (t < 384) {
        int cc = t >> 3, nh = t & 7;
        float a0 = -expf(A_log[dir * CCH * NST + cc * NST + nh]) * LOG2E;
        float a1 = -expf(A_log[dir * CCH * NST + cc * NST + nh + 8]) * LOG2E;
        const float4* dt4 = (const float4*)&dtsT[cc * 68];
        const float4* ux4 = (const float4*)&uxT[cc * 68];
        const float4* B4a = (const float4*)&BcsT[nh * 68];
        const float4* B4b = (const float4*)&BcsT[(nh + 8) * 68];
        const float4* C4a = (const float4*)&CcsT[nh * 68];
        const float4* C4b = (const float4*)&CcsT[(nh + 8) * 68];
        float h0 = 0.f, h1 = 0.f;

#define STEP(COMP, LIDX)                                                    \
        {                                                                   \
            float e0 = __builtin_amdgcn_exp2f(dtv.COMP * a0);               \
            float e1 = __builtin_amdgcn_exp2f(dtv.COMP * a1);               \
            h0 = fmaf(e0, h0, uxv.COMP * Bva.COMP);                         \
            h1 = fmaf(e1, h1, uxv.COMP * Bvb.COMP);                         \
            float p = fmaf(h1, Cvb.COMP, h0 * Cva.COMP);                    \
            p = dpp_add<0xB1>(p);                                           \
            p = dpp_add<0x4E>(p);                                           \
            p = dpp_add<0x141>(p);                                          \
            if (nh == 0) ys[(LIDX) * CCH + cc] = p;                         \
        }

#pragma unroll
        for (int l4 = 0; l4 < 16; ++l4) {
            float4 dtv = dt4[l4];
            float4 uxv = ux4[l4];
            float4 Bva = B4a[l4];
            float4 Bvb = B4b[l4];
            float4 Cva = C4a[l4];
            float4 Cvb = C4b[l4];
            STEP(x, l4 * 4 + 0)
            STEP(y, l4 * 4 + 1)
            STEP(z, l4 * 4 + 2)
            STEP(w, l4 * 4 + 3)
        }
#undef STEP
    }
    __syncthreads();

    // ---- epilogue (compile-time specialized per MODE) ----
    if constexpr (MODE != 2) {
        // dir0/dir1: add skip and write/accumulate yws (coalesced)
        int q = t % 12, l = t / 12;
        float4 yv = *(const float4*)&ys[l * CCH + 4 * q];
        float4 xv = *(const float4*)&xs[l * CCH + 4 * q];
        float4 dv = *(const float4*)&D_skip[dir * CCH + 4 * q];
        yv.x = fmaf(dv.x, xv.x, yv.x);
        yv.y = fmaf(dv.y, xv.y, yv.y);
        yv.z = fmaf(dv.z, xv.z, yv.z);
        yv.w = fmaf(dv.w, xv.w, yv.w);
        float* gp = &yws[(vbase + l * stride_v) * CCH + 4 * q];
        if constexpr (MODE == 1) {
            float4 old = *(const float4*)gp;
            yv.x += old.x; yv.y += old.y; yv.z += old.z; yv.w += old.w;
        }
        *(float4*)gp = yv;
    } else {
        // dir2 FINAL: pass 1 -- (q,l) map: coalesced yws read + skip + ys,
        // store to yf (stride 52, float4-aligned, bank-spread).
        {
            int q = t % 12, l = t / 12;
            float4 yv = *(const float4*)&ys[l * CCH + 4 * q];
            float4 xv = *(const float4*)&xs[l * CCH + 4 * q];
            float4 dv = *(const float4*)&D_skip[dir * CCH + 4 * q];
            float4 ov = *(const float4*)&yws[(vbase + l * stride_v) * CCH + 4 * q];
            yv.x = fmaf(dv.x, xv.x, yv.x) + ov.x;
            yv.y = fmaf(dv.y, xv.y, yv.y) + ov.y;
            yv.z = fmaf(dv.z, xv.z, yv.z) + ov.z;
            yv.w = fmaf(dv.w, xv.w, yv.w) + ov.w;
            *(float4*)&yf[l * 52 + 4 * q] = yv;
        }
        __syncthreads();
        // pass 2 -- (c,l0) map: transpose in LDS, coalesced float4 out-write.
        // line is voxel-contiguous (dir2 stride 1): out[c*VOX + vbase + 4*l0].
        {
            int l0 = t & 15, c = t >> 4;
            float4 o;
            o.x = yf[(4 * l0 + 0) * 52 + c];
            o.y = yf[(4 * l0 + 1) * 52 + c];
            o.z = yf[(4 * l0 + 2) * 52 + c];
            o.w = yf[(4 * l0 + 3) * 52 + c];
            *(float4*)&outf[(size_t)c * VOX + vbase + 4 * l0] = o;
        }
    }
}

extern "C" void kernel_launch(void* const* d_in, const int* in_sizes, int n_in,
                              void* d_out, int out_size, void* d_ws, size_t ws_size,
                              hipStream_t stream) {
    const float* x      = (const float*)d_in[0];
    const float* A_log  = (const float*)d_in[1];
    const float* W_dt   = (const float*)d_in[2];
    const float* b_dt   = (const float*)d_in[3];
    const float* W_B    = (const float*)d_in[4];
    const float* W_C    = (const float*)d_in[5];
    const float* D_skip = (const float*)d_in[6];
    float* out = (float*)d_out;

    float* xt  = (float*)d_ws;
    float* yws = xt + (size_t)VOX * CCH;

    k_transpose_in<<<VOX / 64, 256, 0, stream>>>(x, xt);
    k_scan<0><<<4096, 768, 0, stream>>>(xt, yws, A_log, W_dt, b_dt, W_B, W_C,
                                        D_skip, out, 0, 4096);
    k_scan<1><<<4096, 768, 0, stream>>>(xt, yws, A_log, W_dt, b_dt, W_B, W_C,
                                        D_skip, out, 1, 64);
    k_scan<2><<<4096, 768, 0, stream>>>(xt, yws, A_log, W_dt, b_dt, W_B, W_C,
                                        D_skip, out, 2, 1);
}

// Round 24
// 331.581 us; speedup vs baseline: 1.1391x; 1.0033x over previous
//
#include <hip/hip_runtime.h>
#include <math.h>

#define CCH 48
#define NST 16
#define VOX (64*64*64)
#define LOG2E 1.44269504088896340736f

typedef __attribute__((ext_vector_type(8))) short bf16x8_t;
typedef __attribute__((ext_vector_type(4))) float f32x4_t;
typedef unsigned short ushort_t;

__device__ __forceinline__ float softplus_f(float s) {
    return fmaxf(s, 0.f) + log1pf(__expf(-fabsf(s)));
}

__device__ __forceinline__ ushort_t f2bf(float f) {
    unsigned u = __float_as_uint(f);
    unsigned r = (u + 0x7FFF + ((u >> 16) & 1)) >> 16;
    return (ushort_t)r;
}

// r15-proven dpp_add form. LEDGER: "fusable" variant (old=src,bound_ctrl=0)
// REGRESSED +11.5us (r20, isolated). This form is load-bearing.
template<int CTRL>
__device__ __forceinline__ float dpp_add(float x) {
    int v = __builtin_amdgcn_update_dpp(0, __float_as_int(x), CTRL, 0xF, 0xF, true);
    return x + __int_as_float(v);
}

__global__ __launch_bounds__(256) void k_transpose_in(const float* __restrict__ x,
                                                      float* __restrict__ xt) {
    __shared__ float tile[CCH * 65];
    int v0 = blockIdx.x * 64;
    int t = threadIdx.x;
#pragma unroll
    for (int i = 0; i < 12; ++i) {
        int idx = t + i * 256;
        int c = idx >> 6, v = idx & 63;
        tile[c * 65 + v] = x[c * VOX + v0 + v];
    }
    __syncthreads();
#pragma unroll
    for (int i = 0; i < 12; ++i) {
        int idx = t + i * 256;
        int v = idx / CCH, c = idx - v * CCH;
        xt[(v0 + v) * CCH + c] = tile[c * 65 + v];
    }
}

// LDS layout (float offsets):
#define OFF_XS    0        // 3072  xs fp32 [l][48]
#define OFF_XB    3072     // 2304  xs bf16 [l][72] (u16; k 48..63 zero pad)
#define OFF_WB16  5376     // 2880  W bf16 [80][72] (rows 0..47 dt^T, 48..63 B^T, 64..79 C^T)
#define OFF_DTS   8256     // 3264  dtsT[c*68+l]
#define OFF_UX    11520    // 3264  uxT[c*68+l]
#define OFF_BC    14784    // 1088  BcsT[n*68+l]
#define OFF_CC    15872    // 1088  CcsT[n*68+l]
#define OFF_YS    3072     // 3072  ys[l*48+c] (aliases XB+WB16 after MFMA phase)
#define OFF_YF    8256     // 3328  yf[l*52+c] (final kernel only; aliases dts/ux)
#define SMEM_FLOATS 16960  // 67,840 B -> 2 blocks/CU

// Ledger (empirical, this kernel):
//  launch_bounds: arg2=6 -> RA cap 40 VGPR; arg2=4/2 -> 64 VGPR -> 1 block/CU
//    (m69 halving), 1.9x latency (r8/r9). KEEP (768,6), live-set <= ~32.
//  r19 (this exact k_scan source): 119.5us/scan, conflicts 3.08e6.
//  r22 runtime-mode branch: all scans +4.8us, conflicts ->5.96e6 (codegen
//    perturbation). r23 template<MODE>: partial recovery (121.7us) but
//    conflicts stayed 5.96e6 -> template siblings still couple (rule #19).
//    THIS round: plain r19 kernel restored verbatim + SEPARATE k_scan_final.
//  exp: __builtin_amdgcn_exp2f = bare v_exp_f32 (r19). libm exp2f REGRESSED
//    (r18 +38us). dpp_add old=0/bound_ctrl=1 load-bearing (r20).
//  scan structure: 2-state/384-thr/6-wave is a LOCAL OPTIMUM (r18/r20/r21 all
//    regressed). Do not micro-opt scan further.
//  Cross-lane: xor-involutions 0xB1/0x4E/0x141 verified (r12); ror 8-lane
//    subsets WRONG (r10). MFMA D: col=lane&15, row=(lane>>4)*4+reg (m89).

#define SCAN_COMMON_BODY(DIR_EXPR)                                            \
    float* xs   = smem + OFF_XS;                                              \
    float* dtsT = smem + OFF_DTS;                                             \
    float* uxT  = smem + OFF_UX;                                              \
    float* BcsT = smem + OFF_BC;                                              \
    float* CcsT = smem + OFF_CC;                                              \
    float* ys   = smem + OFF_YS;                                              \
    ushort_t* xb = (ushort_t*)(smem + OFF_XB);                                \
    ushort_t* wb = (ushort_t*)(smem + OFF_WB16);                              \
    (void)ys;

// ---- r19-verbatim scan kernel (dir0/dir1: write or accumulate yws) ----
__global__ __launch_bounds__(768, 6) void k_scan(
    const float* __restrict__ xt, float* __restrict__ yws,
    const float* __restrict__ A_log, const float* __restrict__ W_dt,
    const float* __restrict__ b_dt, const float* __restrict__ W_B,
    const float* __restrict__ W_C, const float* __restrict__ D_skip,
    int dir, int stride_v, int accumulate)
{
    __shared__ __align__(16) float smem[SMEM_FLOATS];
    SCAN_COMMON_BODY(dir)

    int t = threadIdx.x;
    int lid = blockIdx.x;
    int a = lid >> 6, b = lid & 63;
    int vbase;
    if (dir == 0) vbase = lid;                 // step stride 4096 (along D)
    else if (dir == 1) vbase = a * 4096 + b;   // step stride 64   (along H)
    else vbase = a * 4096 + b * 64;            // step stride 1    (along W)

    const float* wdt_g = W_dt + dir * CCH * CCH;
    const float* wB_g  = W_B + dir * CCH * NST;
    const float* wC_g  = W_C + dir * CCH * NST;

    // ---- stage line of x: fp32 + bf16 copies ----
    {
        int q = t % 12, l = t / 12;
        float4 v = *(const float4*)&xt[(vbase + l * stride_v) * CCH + 4 * q];
        *(float4*)&xs[l * CCH + 4 * q] = v;
        unsigned p0 = (unsigned)f2bf(v.x) | ((unsigned)f2bf(v.y) << 16);
        unsigned p1 = (unsigned)f2bf(v.z) | ((unsigned)f2bf(v.w) << 16);
        unsigned* d = (unsigned*)&xb[l * 72 + 4 * q];
        d[0] = p0; d[1] = p1;
    }
    // ---- stage weights bf16, transposed ----
    for (int idx = t; idx < 3840; idx += 768) {
        float v; int row, k;
        if (idx < 2304)      { k = idx / 48;       row = idx % 48;        v = wdt_g[idx]; }
        else if (idx < 3072) { int j = idx - 2304; k = j >> 4; row = 48 + (j & 15); v = wB_g[j]; }
        else                 { int j = idx - 3072; k = j >> 4; row = 64 + (j & 15); v = wC_g[j]; }
        wb[row * 72 + k] = f2bf(v);
    }
    for (int i = t; i < 80 * 16; i += 768) wb[(i >> 4) * 72 + 48 + (i & 15)] = 0;
    for (int i = t; i < 64 * 16; i += 768) xb[(i >> 4) * 72 + 48 + (i & 15)] = 0;
    __syncthreads();

    // ---- MFMA projections ----
    {
        int w = t >> 6, lane = t & 63;
        if (w < 10) {
            int r16 = lane & 15, g = lane >> 4;
#pragma unroll
            for (int tt = 0; tt < 2; ++tt) {
                int tile = w * 2 + tt;
                int tm = tile >> 2, tn = tile & 3;
                const ushort_t* ap = &wb[(tm * 16 + r16) * 72 + g * 8];
                const ushort_t* bp = &xb[(tn * 16 + r16) * 72 + g * 8];
                bf16x8_t A0 = *(const bf16x8_t*)ap;
                bf16x8_t A1 = *(const bf16x8_t*)(ap + 32);
                bf16x8_t B0 = *(const bf16x8_t*)bp;
                bf16x8_t B1 = *(const bf16x8_t*)(bp + 32);
                f32x4_t acc = {0.f, 0.f, 0.f, 0.f};
                acc = __builtin_amdgcn_mfma_f32_16x16x32_bf16(A0, B0, acc, 0, 0, 0);
                acc = __builtin_amdgcn_mfma_f32_16x16x32_bf16(A1, B1, acc, 0, 0, 0);
                int col = tn * 16 + r16;
                float* outp;
                if (tm < 3)       outp = &dtsT[(tm * 16 + g * 4) * 68 + col];
                else if (tm == 3) outp = &BcsT[(g * 4) * 68 + col];
                else              outp = &CcsT[(g * 4) * 68 + col];
                outp[0 * 68] = acc[0];
                outp[1 * 68] = acc[1];
                outp[2 * 68] = acc[2];
                outp[3 * 68] = acc[3];
            }
        }
    }
    __syncthreads();

    // ---- pointwise: bias + softplus on dt; ux = dt * x ----
    {
        int c = t % CCH, l0 = t / CCH;
        float bias = b_dt[dir * CCH + c];
        float4 dv = *(const float4*)&dtsT[c * 68 + 4 * l0];
        float4 dtv, uxv;
        dtv.x = softplus_f(dv.x + bias); uxv.x = dtv.x * xs[(4 * l0 + 0) * CCH + c];
        dtv.y = softplus_f(dv.y + bias); uxv.y = dtv.y * xs[(4 * l0 + 1) * CCH + c];
        dtv.z = softplus_f(dv.z + bias); uxv.z = dtv.z * xs[(4 * l0 + 2) * CCH + c];
        dtv.w = softplus_f(dv.w + bias); uxv.w = dtv.w * xs[(4 * l0 + 3) * CCH + c];
        *(float4*)&dtsT[c * 68 + 4 * l0] = dtv;
        *(float4*)&uxT[c * 68 + 4 * l0]  = uxv;
    }
    __syncthreads();

    // ---- sequential scan: 384 threads, TWO states ----
    if (t < 384) {
        int cc = t >> 3, nh = t & 7;
        float a0 = -expf(A_log[dir * CCH * NST + cc * NST + nh]) * LOG2E;
        float a1 = -expf(A_log[dir * CCH * NST + cc * NST + nh + 8]) * LOG2E;
        const float4* dt4 = (const float4*)&dtsT[cc * 68];
        const float4* ux4 = (const float4*)&uxT[cc * 68];
        const float4* B4a = (const float4*)&BcsT[nh * 68];
        const float4* B4b = (const float4*)&BcsT[(nh + 8) * 68];
        const float4* C4a = (const float4*)&CcsT[nh * 68];
        const float4* C4b = (const float4*)&CcsT[(nh + 8) * 68];
        float h0 = 0.f, h1 = 0.f;

#define STEP(COMP, LIDX)                                                    \
        {                                                                   \
            float e0 = __builtin_amdgcn_exp2f(dtv.COMP * a0);               \
            float e1 = __builtin_amdgcn_exp2f(dtv.COMP * a1);               \
            h0 = fmaf(e0, h0, uxv.COMP * Bva.COMP);                         \
            h1 = fmaf(e1, h1, uxv.COMP * Bvb.COMP);                         \
            float p = fmaf(h1, Cvb.COMP, h0 * Cva.COMP);                    \
            p = dpp_add<0xB1>(p);                                           \
            p = dpp_add<0x4E>(p);                                           \
            p = dpp_add<0x141>(p);                                          \
            if (nh == 0) ys[(LIDX) * CCH + cc] = p;                         \
        }

#pragma unroll
        for (int l4 = 0; l4 < 16; ++l4) {
            float4 dtv = dt4[l4];
            float4 uxv = ux4[l4];
            float4 Bva = B4a[l4];
            float4 Bvb = B4b[l4];
            float4 Cva = C4a[l4];
            float4 Cvb = C4b[l4];
            STEP(x, l4 * 4 + 0)
            STEP(y, l4 * 4 + 1)
            STEP(z, l4 * 4 + 2)
            STEP(w, l4 * 4 + 3)
        }
#undef STEP
    }
    __syncthreads();

    // ---- add skip term and write/accumulate to yws ----
    {
        int q = t % 12, l = t / 12;
        float4 yv = *(const float4*)&ys[l * CCH + 4 * q];
        float4 xv = *(const float4*)&xs[l * CCH + 4 * q];
        float4 dv = *(const float4*)&D_skip[dir * CCH + 4 * q];
        yv.x = fmaf(dv.x, xv.x, yv.x);
        yv.y = fmaf(dv.y, xv.y, yv.y);
        yv.z = fmaf(dv.z, xv.z, yv.z);
        yv.w = fmaf(dv.w, xv.w, yv.w);
        float* gp = &yws[(vbase + l * stride_v) * CCH + 4 * q];
        if (accumulate) {
            float4 old = *(const float4*)gp;
            yv.x += old.x; yv.y += old.y; yv.z += old.z; yv.w += old.w;
        }
        *(float4*)gp = yv;
    }
}

// ---- dir2 final kernel: scan + fused transposed output write ----
__global__ __launch_bounds__(768, 6) void k_scan_final(
    const float* __restrict__ xt, const float* __restrict__ yws,
    const float* __restrict__ A_log, const float* __restrict__ W_dt,
    const float* __restrict__ b_dt, const float* __restrict__ W_B,
    const float* __restrict__ W_C, const float* __restrict__ D_skip,
    float* __restrict__ outf)
{
    __shared__ __align__(16) float smem[SMEM_FLOATS];
    SCAN_COMMON_BODY(2)
    float* yf = smem + OFF_YF;
    const int dir = 2, stride_v = 1;

    int t = threadIdx.x;
    int lid = blockIdx.x;
    int a = lid >> 6, b = lid & 63;
    int vbase = a * 4096 + b * 64;

    const float* wdt_g = W_dt + dir * CCH * CCH;
    const float* wB_g  = W_B + dir * CCH * NST;
    const float* wC_g  = W_C + dir * CCH * NST;

    {
        int q = t % 12, l = t / 12;
        float4 v = *(const float4*)&xt[(vbase + l * stride_v) * CCH + 4 * q];
        *(float4*)&xs[l * CCH + 4 * q] = v;
        unsigned p0 = (unsigned)f2bf(v.x) | ((unsigned)f2bf(v.y) << 16);
        unsigned p1 = (unsigned)f2bf(v.z) | ((unsigned)f2bf(v.w) << 16);
        unsigned* d = (unsigned*)&xb[l * 72 + 4 * q];
        d[0] = p0; d[1] = p1;
    }
    for (int idx = t; idx < 3840; idx += 768) {
        float v; int row, k;
        if (idx < 2304)      { k = idx / 48;       row = idx % 48;        v = wdt_g[idx]; }
        else if (idx < 3072) { int j = idx - 2304; k = j >> 4; row = 48 + (j & 15); v = wB_g[j]; }
        else                 { int j = idx - 3072; k = j >> 4; row = 64 + (j & 15); v = wC_g[j]; }
        wb[row * 72 + k] = f2bf(v);
    }
    for (int i = t; i < 80 * 16; i += 768) wb[(i >> 4) * 72 + 48 + (i & 15)] = 0;
    for (int i = t; i < 64 * 16; i += 768) xb[(i >> 4) * 72 + 48 + (i & 15)] = 0;
    __syncthreads();

    {
        int w = t >> 6, lane = t & 63;
        if (w < 10) {
            int r16 = lane & 15, g = lane >> 4;
#pragma unroll
            for (int tt = 0; tt < 2; ++tt) {
                int tile = w * 2 + tt;
                int tm = tile >> 2, tn = tile & 3;
                const ushort_t* ap = &wb[(tm * 16 + r16) * 72 + g * 8];
                const ushort_t* bp = &xb[(tn * 16 + r16) * 72 + g * 8];
                bf16x8_t A0 = *(const bf16x8_t*)ap;
                bf16x8_t A1 = *(const bf16x8_t*)(ap + 32);
                bf16x8_t B0 = *(const bf16x8_t*)bp;
                bf16x8_t B1 = *(const bf16x8_t*)(bp + 32);
                f32x4_t acc = {0.f, 0.f, 0.f, 0.f};
                acc = __builtin_amdgcn_mfma_f32_16x16x32_bf16(A0, B0, acc, 0, 0, 0);
                acc = __builtin_amdgcn_mfma_f32_16x16x32_bf16(A1, B1, acc, 0, 0, 0);
                int col = tn * 16 + r16;
                float* outp;
                if (tm < 3)       outp = &dtsT[(tm * 16 + g * 4) * 68 + col];
                else if (tm == 3) outp = &BcsT[(g * 4) * 68 + col];
                else              outp = &CcsT[(g * 4) * 68 + col];
                outp[0 * 68] = acc[0];
                outp[1 * 68] = acc[1];
                outp[2 * 68] = acc[2];
                outp[3 * 68] = acc[3];
            }
        }
    }
    __syncthreads();

    {
        int c = t % CCH, l0 = t / CCH;
        float bias = b_dt[dir * CCH + c];
        float4 dv = *(const float4*)&dtsT[c * 68 + 4 * l0];
        float4 dtv, uxv;
        dtv.x = softplus_f(dv.x + bias); uxv.x = dtv.x * xs[(4 * l0 + 0) * CCH + c];
        dtv.y = softplus_f(dv.y + bias); uxv.y = dtv.y * xs[(4 * l0 + 1) * CCH + c];
        dtv.z = softplus_f(dv.z + bias); uxv.z = dtv.z * xs[(4 * l0 + 2) * CCH + c];
        dtv.w = softplus_f(dv.w + bias); uxv.w = dtv.w * xs[(4 * l0 + 3) * CCH + c];
        *(float4*)&dtsT[c * 68 + 4 * l0] = dtv;
        *(float4*)&uxT[c * 68 + 4 * l0]  = uxv;
    }
    __syncthreads();

    if (t < 384) {
        int cc = t >> 3, nh = t & 7;
        float a0 = -expf(A_log[dir * CCH * NST + cc * NST + nh]) * LOG2E;
        float a1 = -expf(A_log[dir * CCH * NST + cc * NST + nh + 8]) * LOG2E;
        const float4* dt4 = (const float4*)&dtsT[cc * 68];
        const float4* ux4 = (const float4*)&uxT[cc * 68];
        const float4* B4a = (const float4*)&BcsT[nh * 68];
        const float4* B4b = (const float4*)&BcsT[(nh + 8) * 68];
        const float4* C4a = (const float4*)&CcsT[nh * 68];
        const float4* C4b = (const float4*)&CcsT[(nh + 8) * 68];
        float h0 = 0.f, h1 = 0.f;

#define STEP(COMP, LIDX)                                                    \
        {                                                                   \
            float e0 = __builtin_amdgcn_exp2f(dtv.COMP * a0);               \
            float e1 = __builtin_amdgcn_exp2f(dtv.COMP * a1);               \
            h0 = fmaf(e0, h0, uxv.COMP * Bva.COMP);                         \
            h1 = fmaf(e1, h1, uxv.COMP * Bvb.COMP);                         \
            float p = fmaf(h1, Cvb.COMP, h0 * Cva.COMP);                    \
            p = dpp_add<0xB1>(p);                                           \
            p = dpp_add<0x4E>(p);                                           \
            p = dpp_add<0x141>(p);                                          \
            if (nh == 0) ys[(LIDX) * CCH + cc] = p;                         \
        }

#pragma unroll
        for (int l4 = 0; l4 < 16; ++l4) {
            float4 dtv = dt4[l4];
            float4 uxv = ux4[l4];
            float4 Bva = B4a[l4];
            float4 Bvb = B4b[l4];
            float4 Cva = C4a[l4];
            float4 Cvb = C4b[l4];
            STEP(x, l4 * 4 + 0)
            STEP(y, l4 * 4 + 1)
            STEP(z, l4 * 4 + 2)
            STEP(w, l4 * 4 + 3)
        }
#undef STEP
    }
    __syncthreads();

    // pass 1: coalesced yws read + skip + ys -> yf (stride 52)
    {
        int q = t % 12, l = t / 12;
        float4 yv = *(const float4*)&ys[l * CCH + 4 * q];
        float4 xv = *(const float4*)&xs[l * CCH + 4 * q];
        float4 dv = *(const float4*)&D_skip[dir * CCH + 4 * q];
        float4 ov = *(const float4*)&yws[(vbase + l * stride_v) * CCH + 4 * q];
        yv.x = fmaf(dv.x, xv.x, yv.x) + ov.x;
        yv.y = fmaf(dv.y, xv.y, yv.y) + ov.y;
        yv.z = fmaf(dv.z, xv.z, yv.z) + ov.z;
        yv.w = fmaf(dv.w, xv.w, yv.w) + ov.w;
        *(float4*)&yf[l * 52 + 4 * q] = yv;
    }
    __syncthreads();
    // pass 2: LDS transpose, coalesced float4 out-write (line voxel-contiguous)
    {
        int l0 = t & 15, c = t >> 4;
        float4 o;
        o.x = yf[(4 * l0 + 0) * 52 + c];
        o.y = yf[(4 * l0 + 1) * 52 + c];
        o.z = yf[(4 * l0 + 2) * 52 + c];
        o.w = yf[(4 * l0 + 3) * 52 + c];
        *(float4*)&outf[(size_t)c * VOX + vbase + 4 * l0] = o;
    }
}

extern "C" void kernel_launch(void* const* d_in, const int* in_sizes, int n_in,
                              void* d_out, int out_size, void* d_ws, size_t ws_size,
                              hipStream_t stream) {
    const float* x      = (const float*)d_in[0];
    const float* A_log  = (const float*)d_in[1];
    const float* W_dt   = (const float*)d_in[2];
    const float* b_dt   = (const float*)d_in[3];
    const float* W_B    = (const float*)d_in[4];
    const float* W_C    = (const float*)d_in[5];
    const float* D_skip = (const float*)d_in[6];
    float* out = (float*)d_out;

    float* xt  = (float*)d_ws;
    float* yws = xt + (size_t)VOX * CCH;

    k_transpose_in<<<VOX / 64, 256, 0, stream>>>(x, xt);
    k_scan<<<4096, 768, 0, stream>>>(xt, yws, A_log, W_dt, b_dt, W_B, W_C,
                                     D_skip, 0, 4096, 0);
    k_scan<<<4096, 768, 0, stream>>>(xt, yws, A_log, W_dt, b_dt, W_B, W_C,
                                     D_skip, 1, 64, 1);
    k_scan_final<<<4096, 768, 0, stream>>>(xt, yws, A_log, W_dt, b_dt, W_B,
                                           W_C, D_skip, out);
}